// Round 1
// baseline (56.284 us; speedup 1.0000x reference)
//
#include <hip/hip_runtime.h>

// Problem constants (fixed by the reference)
#define B_ROWS   512
#define C_COLS   65536
#define CHUNKS   4           // chunks per row
#define T1       256         // threads, kernel 1
#define T2       512         // threads, kernel 2
// per chunk: C/CHUNKS = 16384 elems = 4096 float4; per thread: 16 float4

__device__ __forceinline__ void wave_reduce4(float& a, float& b, float& c, float& d) {
    #pragma unroll
    for (int off = 32; off >= 1; off >>= 1) {
        a += __shfl_down(a, off);
        b += __shfl_down(b, off);
        c += __shfl_down(c, off);
        d += __shfl_down(d, off);
    }
}

// Kernel 1: per-(row,chunk) partial sums -> ws[blk] = {num, a2, b2, bce_w}
__global__ __launch_bounds__(T1) void coscel_partial(
    const float* __restrict__ pred,
    const float* __restrict__ tgt,
    const float* __restrict__ cw,
    const float* __restrict__ bw,
    float4* __restrict__ ws)
{
    const int blk   = blockIdx.x;          // 0 .. B_ROWS*CHUNKS-1
    const int row   = blk >> 2;            // / CHUNKS
    const int chunk = blk & (CHUNKS - 1);
    const int tid   = threadIdx.x;

    const size_t base   = (size_t)row * C_COLS + (size_t)chunk * (C_COLS / CHUNKS);
    const size_t wbase  = (size_t)chunk * (C_COLS / CHUNKS);

    const float4* __restrict__ p4 = (const float4*)(pred + base);
    const float4* __restrict__ t4 = (const float4*)(tgt  + base);
    const float4* __restrict__ w4 = (const float4*)(cw   + wbase);
    const float4* __restrict__ g4 = (const float4*)(bw   + wbase);

    float num = 0.f, a2 = 0.f, b2 = 0.f, bce = 0.f;

    #pragma unroll 4
    for (int i = 0; i < 16; ++i) {
        const int idx = i * T1 + tid;       // coalesced
        const float4 p = p4[idx];
        const float4 t = t4[idx];
        const float4 w = w4[idx];
        const float4 g = g4[idx];

        #define DO_COMP(comp)                                              \
        {                                                                  \
            const float a = t.comp * w.comp;                               \
            const float b = p.comp * w.comp;                               \
            num += a * b;                                                  \
            a2  += a * a;                                                  \
            b2  += b * b;                                                  \
            const float x = t.comp, y = p.comp;                            \
            const float e = __expf(-fabsf(x));                             \
            const float l = __logf(1.0f + e);                              \
            bce += g.comp * (fmaxf(x, 0.0f) - x * y + l);                  \
        }
        DO_COMP(x) DO_COMP(y) DO_COMP(z) DO_COMP(w)
        #undef DO_COMP
    }

    wave_reduce4(num, a2, b2, bce);

    __shared__ float4 sred[T1 / 64];
    const int lane = tid & 63, wid = tid >> 6;
    if (lane == 0) sred[wid] = make_float4(num, a2, b2, bce);
    __syncthreads();
    if (tid == 0) {
        float4 r = sred[0];
        #pragma unroll
        for (int i = 1; i < T1 / 64; ++i) {
            const float4 s = sred[i];
            r.x += s.x; r.y += s.y; r.z += s.z; r.w += s.w;
        }
        ws[blk] = r;
    }
}

// Kernel 2: fold chunk partials per row, cosine per row, global sums, final scalar.
__global__ __launch_bounds__(T2) void coscel_final(
    const float4* __restrict__ ws,
    const float* __restrict__ bw,
    float* __restrict__ out)
{
    const int tid = threadIdx.x;

    // One thread per row (T2 == B_ROWS)
    float num = 0.f, a2 = 0.f, b2 = 0.f, bce = 0.f;
    #pragma unroll
    for (int c = 0; c < CHUNKS; ++c) {
        const float4 v = ws[(size_t)tid * CHUNKS + c];
        num += v.x; a2 += v.y; b2 += v.z; bce += v.w;
    }
    const float na = fmaxf(sqrtf(a2), 1e-8f);
    const float nb = fmaxf(sqrtf(b2), 1e-8f);
    float cosv = num / (na * nb);

    // Denominator: sum of bce_weights over C
    float wsum = 0.f;
    const float4* g4 = (const float4*)bw;
    for (int i = tid; i < C_COLS / 4; i += T2) {
        const float4 g = g4[i];
        wsum += g.x + g.y + g.z + g.w;
    }

    // Block reduction of {cosv, bce, wsum} across 8 waves
    #pragma unroll
    for (int off = 32; off >= 1; off >>= 1) {
        cosv += __shfl_down(cosv, off);
        bce  += __shfl_down(bce,  off);
        wsum += __shfl_down(wsum, off);
    }
    __shared__ float s0[T2 / 64], s1[T2 / 64], s2[T2 / 64];
    const int lane = tid & 63, wid = tid >> 6;
    if (lane == 0) { s0[wid] = cosv; s1[wid] = bce; s2[wid] = wsum; }
    __syncthreads();
    if (tid == 0) {
        float cs = 0.f, bs = 0.f, wss = 0.f;
        #pragma unroll
        for (int i = 0; i < T2 / 64; ++i) { cs += s0[i]; bs += s1[i]; wss += s2[i]; }
        const float cosine_loss   = -(cs / (float)B_ROWS);
        const float sub_graph     = bs / (wss + 1e-10f);
        out[0] = cosine_loss + sub_graph / 10.0f;
    }
}

extern "C" void kernel_launch(void* const* d_in, const int* in_sizes, int n_in,
                              void* d_out, int out_size, void* d_ws, size_t ws_size,
                              hipStream_t stream) {
    const float* pred = (const float*)d_in[0];   // prediction (B, C)
    const float* tgt  = (const float*)d_in[1];   // target     (B, C)
    const float* cw   = (const float*)d_in[2];   // cos_weights (C,)
    const float* bw   = (const float*)d_in[3];   // bce_weights (C,)
    float* out = (float*)d_out;
    float4* ws = (float4*)d_ws;                  // B_ROWS*CHUNKS float4 = 32 KiB

    coscel_partial<<<B_ROWS * CHUNKS, T1, 0, stream>>>(pred, tgt, cw, bw, ws);
    coscel_final<<<1, T2, 0, stream>>>(ws, bw, out);
}

// Round 2
// 51.126 us; speedup vs baseline: 1.1009x; 1.1009x over previous
//
#include <hip/hip_runtime.h>

// Problem constants (fixed by the reference)
#define B_ROWS   512
#define C_COLS   65536
#define BR       4                    // rows per block
#define CCH      4096                 // columns per chunk
#define NCH      (C_COLS / CCH)       // 16 chunks per row
#define RG       (B_ROWS / BR)        // 128 row-groups
#define T1       256                  // threads, kernel 1
#define ITERS    (CCH / 4 / T1)       // 4 float4 per thread per stream
#define T2       512                  // threads, kernel 2 (== B_ROWS)

// ws layout: [0 .. B_ROWS*NCH) float4 row-chunk partials {num,a2,b2,bce}
//            then NCH floats: per-chunk sum of bce_weights
#define WS_F4_COUNT (B_ROWS * NCH)

__device__ __forceinline__ void wave_reduce4(float& a, float& b, float& c, float& d) {
    #pragma unroll
    for (int off = 32; off >= 1; off >>= 1) {
        a += __shfl_down(a, off);
        b += __shfl_down(b, off);
        c += __shfl_down(c, off);
        d += __shfl_down(d, off);
    }
}

// Kernel 1: each block = 4 rows x one 4096-col chunk.
// Weights loaded once per block serve all 4 rows.
__global__ __launch_bounds__(T1) void coscel_partial(
    const float* __restrict__ pred,
    const float* __restrict__ tgt,
    const float* __restrict__ cw,
    const float* __restrict__ bw,
    float4* __restrict__ ws)
{
    const int blk  = blockIdx.x;          // 0 .. RG*NCH-1 (2048)
    const int rowg = blk / NCH;
    const int ch   = blk % NCH;
    const int tid  = threadIdx.x;

    const int row0 = rowg * BR;
    const size_t cbase = (size_t)ch * CCH;

    const float4* __restrict__ w4 = (const float4*)(cw + cbase);
    const float4* __restrict__ g4 = (const float4*)(bw + cbase);
    const float4* p4[BR];
    const float4* t4[BR];
    #pragma unroll
    for (int r = 0; r < BR; ++r) {
        p4[r] = (const float4*)(pred + (size_t)(row0 + r) * C_COLS + cbase);
        t4[r] = (const float4*)(tgt  + (size_t)(row0 + r) * C_COLS + cbase);
    }

    float num[BR], a2[BR], b2[BR], bce[BR];
    #pragma unroll
    for (int r = 0; r < BR; ++r) { num[r] = a2[r] = b2[r] = bce[r] = 0.f; }
    float gsum = 0.f;

    #pragma unroll 2
    for (int i = 0; i < ITERS; ++i) {
        const int idx = i * T1 + tid;     // coalesced
        const float4 w = w4[idx];
        const float4 g = g4[idx];
        gsum += g.x + g.y + g.z + g.w;

        float4 pv[BR], tv[BR];
        #pragma unroll
        for (int r = 0; r < BR; ++r) { pv[r] = p4[r][idx]; tv[r] = t4[r][idx]; }

        #pragma unroll
        for (int r = 0; r < BR; ++r) {
            #define DO_COMP(comp)                                            \
            {                                                                \
                const float x = tv[r].comp, y = pv[r].comp;                  \
                const float a = x * w.comp;                                  \
                const float b = y * w.comp;                                  \
                num[r] += a * b;                                             \
                a2[r]  += a * a;                                             \
                b2[r]  += b * b;                                             \
                const float e = __expf(-fabsf(x));                           \
                const float l = __logf(1.0f + e);                            \
                bce[r] += g.comp * (fmaxf(x, 0.0f) - x * y + l);             \
            }
            DO_COMP(x) DO_COMP(y) DO_COMP(z) DO_COMP(w)
            #undef DO_COMP
        }
    }

    // Reduce each row's 4 values across the wave, plus gsum.
    #pragma unroll
    for (int r = 0; r < BR; ++r) wave_reduce4(num[r], a2[r], b2[r], bce[r]);
    #pragma unroll
    for (int off = 32; off >= 1; off >>= 1) gsum += __shfl_down(gsum, off);

    __shared__ float4 sred[T1 / 64][BR];
    __shared__ float  sg[T1 / 64];
    const int lane = tid & 63, wid = tid >> 6;
    if (lane == 0) {
        #pragma unroll
        for (int r = 0; r < BR; ++r) sred[wid][r] = make_float4(num[r], a2[r], b2[r], bce[r]);
        sg[wid] = gsum;
    }
    __syncthreads();
    if (tid == 0) {
        #pragma unroll
        for (int r = 0; r < BR; ++r) {
            float4 acc = sred[0][r];
            #pragma unroll
            for (int w_ = 1; w_ < T1 / 64; ++w_) {
                const float4 s = sred[w_][r];
                acc.x += s.x; acc.y += s.y; acc.z += s.z; acc.w += s.w;
            }
            ws[(size_t)(row0 + r) * NCH + ch] = acc;
        }
        if (rowg == 0) {
            float gs = sg[0] + sg[1] + sg[2] + sg[3];
            ((float*)(ws + WS_F4_COUNT))[ch] = gs;
        }
    }
}

// Kernel 2: fold chunk partials per row, cosine per row, global sums, final scalar.
__global__ __launch_bounds__(T2) void coscel_final(
    const float4* __restrict__ ws,
    float* __restrict__ out)
{
    const int tid = threadIdx.x;    // == row

    float num = 0.f, a2 = 0.f, b2 = 0.f, bce = 0.f;
    #pragma unroll
    for (int c = 0; c < NCH; ++c) {
        const float4 v = ws[(size_t)tid * NCH + c];
        num += v.x; a2 += v.y; b2 += v.z; bce += v.w;
    }
    const float na = fmaxf(sqrtf(a2), 1e-8f);
    const float nb = fmaxf(sqrtf(b2), 1e-8f);
    float cosv = num / (na * nb);

    const float* wpart = (const float*)(ws + WS_F4_COUNT);
    float wsum = (tid < NCH) ? wpart[tid] : 0.f;

    #pragma unroll
    for (int off = 32; off >= 1; off >>= 1) {
        cosv += __shfl_down(cosv, off);
        bce  += __shfl_down(bce,  off);
        wsum += __shfl_down(wsum, off);
    }
    __shared__ float s0[T2 / 64], s1[T2 / 64], s2[T2 / 64];
    const int lane = tid & 63, wid = tid >> 6;
    if (lane == 0) { s0[wid] = cosv; s1[wid] = bce; s2[wid] = wsum; }
    __syncthreads();
    if (tid == 0) {
        float cs = 0.f, bs = 0.f, wss = 0.f;
        #pragma unroll
        for (int i = 0; i < T2 / 64; ++i) { cs += s0[i]; bs += s1[i]; wss += s2[i]; }
        const float cosine_loss = -(cs / (float)B_ROWS);
        const float sub_graph   = bs / (wss + 1e-10f);
        out[0] = cosine_loss + sub_graph / 10.0f;
    }
}

extern "C" void kernel_launch(void* const* d_in, const int* in_sizes, int n_in,
                              void* d_out, int out_size, void* d_ws, size_t ws_size,
                              hipStream_t stream) {
    const float* pred = (const float*)d_in[0];   // prediction (B, C)
    const float* tgt  = (const float*)d_in[1];   // target     (B, C)
    const float* cw   = (const float*)d_in[2];   // cos_weights (C,)
    const float* bw   = (const float*)d_in[3];   // bce_weights (C,)
    float* out = (float*)d_out;
    float4* ws = (float4*)d_ws;                  // 128 KiB partials + 64 B wsum

    coscel_partial<<<RG * NCH, T1, 0, stream>>>(pred, tgt, cw, bw, ws);
    coscel_final<<<1, T2, 0, stream>>>(ws, out);
}